// Round 13
// baseline (285.880 us; speedup 1.0000x reference)
//
#include <hip/hip_runtime.h>
#include <hip/hip_bf16.h>

#define HEADS 4
#define KCL 4
#define NBUCK 256
#define BCAP 4096            // bucket capacity (mean 3125, +17 sigma)
#define EPT 8                // edges per thread in k_bin
typedef unsigned long long u64;
typedef short short8 __attribute__((ext_vector_type(8)));
typedef float f32x4 __attribute__((ext_vector_type(4)));

__device__ __forceinline__ unsigned short bf16_rne(float f) {
    unsigned int u = __float_as_uint(f);
    u += 0x7FFFu + ((u >> 16) & 1u);
    return (unsigned short)(u >> 16);
}

// packed edge: [ea:32][dstlo:8][src:24]

// ---------------------------------------------------------------- k_bin: pass 1 — coarse-bucket append
__global__ __launch_bounds__(256) void k_bin(const int* __restrict__ src, const int* __restrict__ dst,
                                             const float* __restrict__ ea,
                                             unsigned int* __restrict__ gtail,
                                             u64* __restrict__ gbuck, int E_, int BW) {
    __shared__ unsigned int cnt[NBUCK];
    __shared__ unsigned int gb[NBUCK];
    int t = threadIdx.x;
    cnt[t] = 0u;
    __syncthreads();
    int e0 = blockIdx.x * (256 * EPT) + t;
    u64 pk[EPT]; int bk[EPT]; unsigned int ls[EPT];
    int m = 0;
#pragma unroll
    for (int i = 0; i < EPT; i++) {
        int e = e0 + i * 256;
        if (e < E_) {
            int s = src[e], d = dst[e];
            float a = ea[e];
            int b = d / BW;
            int lo = d - b * BW;
            pk[m] = ((u64)__float_as_uint(a) << 32) | ((u64)(unsigned int)lo << 24) | (unsigned int)s;
            bk[m] = b;
            ls[m] = atomicAdd(&cnt[b], 1u);
            m++;
        }
    }
    __syncthreads();
    gb[t] = (cnt[t] > 0u) ? atomicAdd(&gtail[t], cnt[t]) : 0u;
    __syncthreads();
    for (int i = 0; i < m; i++) {
        unsigned int pos = gb[bk[i]] + ls[i];
        if (pos < BCAP) gbuck[(size_t)bk[i] * BCAP + pos] = pk[i];
    }
}

// ---------------------------------------------------------------- k_scatter2: pass 2 — row-pack within bucket
__global__ __launch_bounds__(256) void k_scatter2(const unsigned int* __restrict__ gtail,
                                                  const u64* __restrict__ gbuck,
                                                  u64* __restrict__ gpacked,
                                                  int2* __restrict__ idx2, int N_, int BW) {
    __shared__ unsigned int rcnt[256], pre[256], cur[256];
    int b = blockIdx.x, t = threadIdx.x;
    unsigned int n = gtail[b]; if (n > BCAP) n = BCAP;
    int r0 = b * BW;
    rcnt[t] = 0u;
    __syncthreads();
    size_t base = (size_t)b * BCAP;
    for (unsigned int pos = t; pos < n; pos += 256) {
        u64 p = gbuck[base + pos];
        int lo = (int)((p >> 24) & 0xFFu);
        atomicAdd(&rcnt[lo], 1u);
    }
    __syncthreads();
    unsigned int v = rcnt[t];
    pre[t] = v;
    __syncthreads();
    for (int off = 1; off < 256; off <<= 1) {
        unsigned int u = (t >= off) ? pre[t - off] : 0u;
        __syncthreads();
        pre[t] += u;
        __syncthreads();
    }
    unsigned int excl = pre[t] - v;
    cur[t] = excl;
    if (t < BW && r0 + t < N_) idx2[r0 + t] = make_int2((int)(base + excl), (int)v);
    __syncthreads();
    for (unsigned int pos = t; pos < n; pos += 256) {
        u64 p = gbuck[base + pos];
        int lo = (int)((p >> 24) & 0xFFu);
        unsigned int slot = atomicAdd(&cur[lo], 1u);
        gpacked[base + slot] = p;
    }
}

// ---------------------------------------------------------------- k_prep_all: ce + u + W2T + per-node prep, one dispatch
// Every block computes P_s1/P_d1 into LDS (cheap, redundant); block 0 writes
// ce1/ce2/u_s/u_d; global idx < 16384 also writes W2T; then per-node prep.
__global__ __launch_bounds__(256) void k_prep_all(const float* __restrict__ x,
                                                  const float* __restrict__ W1, const float* __restrict__ W2,
                                                  const float* __restrict__ as1, const float* __restrict__ ad1,
                                                  const float* __restrict__ as2, const float* __restrict__ ad2,
                                                  const float* __restrict__ We1, const float* __restrict__ ae1,
                                                  const float* __restrict__ We2, const float* __restrict__ ae2,
                                                  float* __restrict__ ce1, float* __restrict__ ce2,
                                                  float* __restrict__ u_s, float* __restrict__ u_d,
                                                  unsigned short* __restrict__ W2T,
                                                  float* __restrict__ xpad,
                                                  float* __restrict__ al_s1, float* __restrict__ al_d1, int N_) {
    __shared__ float Ps_l[7][4], Pd_l[7][4];
    int t = threadIdx.x, h = t >> 6, lane = t & 63;
    for (int i = 0; i < 7; i++) {
        float a = W1[i * 256 + t];             // t = h*64+c
        float ps = a * as1[t];
        float pd = a * ad1[t];
        for (int off = 32; off; off >>= 1) {
            ps += __shfl_down(ps, off, 64);
            pd += __shfl_down(pd, off, 64);
        }
        if (lane == 0) { Ps_l[i][h] = ps; Pd_l[i][h] = pd; }
    }
    if (blockIdx.x == 0) {
        float p = We1[t] * ae1[t];
        for (int off = 32; off; off >>= 1) p += __shfl_down(p, off, 64);
        if (lane == 0) ce1[h] = p;
        if (t < 64) {
            float q = We2[t] * ae2[t];
            for (int off = 32; off; off >>= 1) q += __shfl_down(q, off, 64);
            if (t == 0) ce2[0] = q;
        }
        float us = 0.f, ud = 0.f;
        const float* wr = W2 + t * 64;
        for (int n = 0; n < 64; n++) { us += wr[n] * as2[n]; ud += wr[n] * ad2[n]; }
        u_s[t] = us; u_d[t] = ud;
    }
    int gidx = blockIdx.x * 256 + t;
    if (gidx < 16384) {
        int nn = gidx & 63, k = gidx >> 6;
        W2T[nn * 256 + k] = bf16_rne(W2[k * 64 + nn]);
    }
    __syncthreads();
    int n = gidx;
    if (n >= N_) return;
    float xv[7];
#pragma unroll
    for (int i = 0; i < 7; i++) xv[i] = x[n * 7 + i];
    ((float4*)(xpad + (size_t)n * 8))[0] = make_float4(xv[0], xv[1], xv[2], xv[3]);
    ((float4*)(xpad + (size_t)n * 8))[1] = make_float4(xv[4], xv[5], xv[6], 0.0f);
    float4 als = make_float4(0.f, 0.f, 0.f, 0.f);
    float4 ald = make_float4(0.f, 0.f, 0.f, 0.f);
#pragma unroll
    for (int i = 0; i < 7; i++) {
        als.x += xv[i] * Ps_l[i][0]; als.y += xv[i] * Ps_l[i][1];
        als.z += xv[i] * Ps_l[i][2]; als.w += xv[i] * Ps_l[i][3];
        ald.x += xv[i] * Pd_l[i][0]; ald.y += xv[i] * Pd_l[i][1];
        ald.z += xv[i] * Pd_l[i][2]; ald.w += xv[i] * Pd_l[i][3];
    }
    ((float4*)al_s1)[n] = als;
    ((float4*)al_d1)[n] = ald;
}

// ---------------------------------------------------------------- k_agg1f: fused edge-softmax + aggregation (conv1)
__global__ __launch_bounds__(256) void k_agg1f(const int2* __restrict__ idx2,
                                               const u64* __restrict__ gpacked,
                                               const float* __restrict__ al_s1,
                                               const float* __restrict__ al_d1,
                                               const float* __restrict__ ce1,
                                               const float* __restrict__ xpad,
                                               float* __restrict__ xacc, int N_) {
    int tid = blockIdx.x * 256 + threadIdx.x;
    int d = tid >> 2, h = tid & 3;
    if (d >= N_) return;
    int2 ix = idx2[d];
    const u64* row = gpacked + ix.x;
    int cnt = ix.y;
    float ald = al_d1[d * 4 + h];
    float ce = ce1[h];
    float4 accA = make_float4(0.f, 0.f, 0.f, 0.f);
    float4 accB = make_float4(0.f, 0.f, 0.f, 0.f);   // .w = wsum
    float easum = 0.0f;
    int j = 0;
    for (; j + 1 < cnt; j += 2) {
        u64 p0 = row[j], p1 = row[j + 1];
        int s0 = (int)(p0 & 0xFFFFFFu), s1 = (int)(p1 & 0xFFFFFFu);
        float a0 = __uint_as_float((unsigned int)(p0 >> 32));
        float a1 = __uint_as_float((unsigned int)(p1 >> 32));
        easum += a0 + a1;
        float v0 = al_s1[s0 * 4 + h] + ald + a0 * ce;
        float v1 = al_s1[s1 * 4 + h] + ald + a1 * ce;
        v0 = v0 > 0.f ? v0 : 0.2f * v0;
        v1 = v1 > 0.f ? v1 : 0.2f * v1;
        float w0 = __expf(v0), w1 = __expf(v1);
        float4 xa0 = ((const float4*)(xpad + (size_t)s0 * 8))[0];
        float4 xb0 = ((const float4*)(xpad + (size_t)s0 * 8))[1];
        float4 xa1 = ((const float4*)(xpad + (size_t)s1 * 8))[0];
        float4 xb1 = ((const float4*)(xpad + (size_t)s1 * 8))[1];
        accA.x += w0 * xa0.x + w1 * xa1.x;
        accA.y += w0 * xa0.y + w1 * xa1.y;
        accA.z += w0 * xa0.z + w1 * xa1.z;
        accA.w += w0 * xa0.w + w1 * xa1.w;
        accB.x += w0 * xb0.x + w1 * xb1.x;
        accB.y += w0 * xb0.y + w1 * xb1.y;
        accB.z += w0 * xb0.z + w1 * xb1.z;
        accB.w += w0 + w1;
    }
    if (j < cnt) {
        u64 p0 = row[j];
        int s0 = (int)(p0 & 0xFFFFFFu);
        float a0 = __uint_as_float((unsigned int)(p0 >> 32));
        easum += a0;
        float v0 = al_s1[s0 * 4 + h] + ald + a0 * ce;
        v0 = v0 > 0.f ? v0 : 0.2f * v0;
        float w0 = __expf(v0);
        float4 xa0 = ((const float4*)(xpad + (size_t)s0 * 8))[0];
        float4 xb0 = ((const float4*)(xpad + (size_t)s0 * 8))[1];
        accA.x += w0 * xa0.x; accA.y += w0 * xa0.y; accA.z += w0 * xa0.z; accA.w += w0 * xa0.w;
        accB.x += w0 * xb0.x; accB.y += w0 * xb0.y; accB.z += w0 * xb0.z;
        accB.w += w0;
    }
    // self-loop: attr = mean of real incoming ea
    {
        float a_self = easum / fmaxf((float)cnt, 1.0f);
        float v = al_s1[d * 4 + h] + ald + a_self * ce;
        v = v > 0.f ? v : 0.2f * v;
        float w = __expf(v);
        float4 xa0 = ((const float4*)(xpad + (size_t)d * 8))[0];
        float4 xb0 = ((const float4*)(xpad + (size_t)d * 8))[1];
        accA.x += w * xa0.x; accA.y += w * xa0.y; accA.z += w * xa0.z; accA.w += w * xa0.w;
        accB.x += w * xb0.x; accB.y += w * xb0.y; accB.z += w * xb0.z;
        accB.w += w;
    }
    float* o = xacc + (size_t)d * 32 + h * 8;
    ((float4*)o)[0] = accA;
    ((float4*)o)[1] = accB;
}

// ---------------------------------------------------------------- k_xw2g: MFMA version, lane-coalesced generation
__global__ __launch_bounds__(256) void k_xw2g(const float* __restrict__ xacc,
                                              const float* __restrict__ W1,
                                              const float* __restrict__ b1,
                                              const unsigned short* __restrict__ W2T,
                                              const float* __restrict__ u_s,
                                              const float* __restrict__ u_d,
                                              float* __restrict__ xw2,
                                              float* __restrict__ al_s2,
                                              float* __restrict__ al_d2, int N_) {
    __shared__ float Xs[16][32];
    __shared__ __align__(16) unsigned short A_lds[16][264];  // k-pad +8 breaks bank alias
    __shared__ float als_p[16], ald_p[16];
    int t = threadIdx.x;
    int m0 = blockIdx.x * 16;
    if (t < 128) {
        int r = t >> 3, off = (t & 7) * 4;
        int n = m0 + r;
        float4 v = (n < N_) ? *(const float4*)(xacc + (size_t)n * 32 + off)
                            : make_float4(0.f, 0.f, 0.f, 0.f);
        *(float4*)&Xs[r][off] = v;
    }
    __syncthreads();
    // generation: row r = t>>4, lane-k kk = t&15
    {
        int r = t >> 4;
        int kk = t & 15;
        float ps = 0.f, pd = 0.f;
#pragma unroll
        for (int h = 0; h < 4; h++) {
            float xv[7];
#pragma unroll
            for (int i = 0; i < 7; i++) xv[i] = Xs[r][h * 8 + i];
            float rw = 1.0f / (Xs[r][h * 8 + 7] + 1e-16f);
#pragma unroll
            for (int q2 = 0; q2 < 4; q2++) {
                int k = h * 64 + q2 * 16 + kk;
                float s = 0.f;
#pragma unroll
                for (int i = 0; i < 7; i++) s += xv[i] * W1[i * 256 + k];
                float v = s * rw + b1[k];
                float a = v > 0.f ? v : (__expf(v) - 1.0f);
                ps += a * u_s[k];
                pd += a * u_d[k];
                A_lds[r][k] = bf16_rne(a);
            }
        }
#pragma unroll
        for (int mdel = 1; mdel < 16; mdel <<= 1) {
            ps += __shfl_xor(ps, mdel, 64);
            pd += __shfl_xor(pd, mdel, 64);
        }
        if (kk == 0) { als_p[r] = ps; ald_p[r] = pd; }
    }
    __syncthreads();
    // MFMA: wave w covers cols w*16..w*16+15
    int w = t >> 6, lane = t & 63;
    int mm = lane & 15, quad = lane >> 4;
    int n0 = w * 16;
    f32x4 acc = {0.f, 0.f, 0.f, 0.f};
    const unsigned short* bptr = W2T + (size_t)(n0 + mm) * 256;
#pragma unroll
    for (int step = 0; step < 8; step++) {
        int kf = step * 32 + quad * 8;
        short8 af = *(const short8*)&A_lds[mm][kf];
        short8 bf = *(const short8*)&bptr[kf];
        acc = __builtin_amdgcn_mfma_f32_16x16x32_bf16(af, bf, acc, 0, 0, 0);
    }
#pragma unroll
    for (int r = 0; r < 4; r++) {
        int row = m0 + quad * 4 + r;
        if (row < N_) xw2[(size_t)row * 64 + n0 + mm] = acc[r];
    }
    if (t < 16 && m0 + t < N_) { al_s2[m0 + t] = als_p[t]; al_d2[m0 + t] = ald_p[t]; }
}

// ---------------------------------------------------------------- k_agg2p: conv2 softmax-aggregate FUSED with cluster pooling
// grid-stride over dst (1 wave per dst per iter); h2 never materialized —
// the finished row goes straight into LDS zsum partials, flushed once per block.
__global__ __launch_bounds__(256) void k_agg2p(const int2* __restrict__ idx2,
                                               const u64* __restrict__ gpacked,
                                               const float* __restrict__ al_s2,
                                               const float* __restrict__ al_d2,
                                               const float* __restrict__ ce2,
                                               const float* __restrict__ xw2,
                                               const float* __restrict__ x,
                                               const int* __restrict__ assign,
                                               float* __restrict__ zsum, float* __restrict__ cntK,
                                               float* __restrict__ cfK, int N_) {
    __shared__ float lz[KCL * 64];
    __shared__ float lc[KCL];
    __shared__ float lf[KCL];
    int t = threadIdx.x, wid = t >> 6, lane = t & 63;
    lz[t] = 0.0f;
    if (t < KCL) { lc[t] = 0.0f; lf[t] = 0.0f; }
    __syncthreads();
    float ce = ce2[0];
    for (int d = blockIdx.x * 4 + wid; d < N_; d += gridDim.x * 4) {
        int2 ix = idx2[d];
        const u64* row = gpacked + ix.x;
        int cnt = ix.y;
        float ald = al_d2[d];
        float acc = 0.0f;
        float wlane = 0.0f, alane = 0.0f;
        for (int pos = 0; pos < cnt; pos += 64) {
            int nle = min(64, cnt - pos);
            float w = 0.0f, a = 0.0f;
            int s = d;
            if (lane < nle) {
                u64 p = row[pos + lane];
                s = (int)(p & 0xFFFFFFu);
                a = __uint_as_float((unsigned int)(p >> 32));
                float v = al_s2[s] + ald + a * ce;
                v = v > 0.f ? v : 0.2f * v;
                w = __expf(v);
            }
            wlane += w;
            alane += a;
            int jj = 0;
            for (; jj + 1 < nle; jj += 2) {
                float wj0 = __uint_as_float(__builtin_amdgcn_readlane(__float_as_uint(w), jj));
                int   sj0 = __builtin_amdgcn_readlane(s, jj);
                float wj1 = __uint_as_float(__builtin_amdgcn_readlane(__float_as_uint(w), jj + 1));
                int   sj1 = __builtin_amdgcn_readlane(s, jj + 1);
                acc += wj0 * xw2[(size_t)sj0 * 64 + lane] + wj1 * xw2[(size_t)sj1 * 64 + lane];
            }
            if (jj < nle) {
                float wj = __uint_as_float(__builtin_amdgcn_readlane(__float_as_uint(w), jj));
                int   sj = __builtin_amdgcn_readlane(s, jj);
                acc += wj * xw2[(size_t)sj * 64 + lane];
            }
        }
        float wsum = wlane, easum = alane;
        for (int off = 32; off; off >>= 1) {
            wsum += __shfl_xor(wsum, off, 64);
            easum += __shfl_xor(easum, off, 64);
        }
        float a_self = easum / fmaxf((float)cnt, 1.0f);
        float v = al_s2[d] + ald + a_self * ce;
        v = v > 0.f ? v : 0.2f * v;
        float w = __expf(v);
        acc += w * xw2[(size_t)d * 64 + lane];
        wsum += w;
        float hval = acc / (wsum + 1e-16f);
        int a = assign[d];
        atomicAdd(&lz[a * 64 + lane], hval);
        if (lane == 0) {
            atomicAdd(&lc[a], 1.0f);
            atomicAdd(&lf[a], x[d * 7 + 6]);
        }
    }
    __syncthreads();
    atomicAdd(&zsum[t], lz[t]);
    if (t < KCL) {
        atomicAdd(&cntK[t], lc[t]);
        atomicAdd(&cfK[t], lf[t]);
    }
}

// ---------------------------------------------------------------- k_head: actor head + outputs
__global__ __launch_bounds__(256) void k_head(const float* __restrict__ zsum, const float* __restrict__ cntK,
                                              const float* __restrict__ cfK, const float* __restrict__ b2,
                                              const float* __restrict__ A1, const float* __restrict__ c1,
                                              const float* __restrict__ A2, const float* __restrict__ c2,
                                              float* __restrict__ out) {
    __shared__ float zcf[KCL][65];
    __shared__ float logits[KCL];
    int t = threadIdx.x;                       // 256
    int k = t >> 6, c = t & 63;
    float cn = cntK[k];
    float z = (cn > 0.f) ? (zsum[k * 64 + c] / fmaxf(cn, 1.0f) + b2[c]) : 0.0f;
    zcf[k][c] = z;
    out[4 + k * 64 + c] = z;                   // z_flat
    if (c == 0) zcf[k][64] = (cn > 0.f) ? (cfK[k] / fmaxf(cn, 1.0f)) : 0.0f;
    __syncthreads();
    if (t < 64) {
        int j = t;
#pragma unroll
        for (int kk = 0; kk < KCL; kk++) {
            float acc = 0.0f;
            for (int i = 0; i < 65; i++) acc += zcf[kk][i] * A1[i * 64 + j];
            float hr = fmaxf(acc + c1[j], 0.0f);
            float contrib = hr * A2[j];
            for (int off = 32; off; off >>= 1) contrib += __shfl_down(contrib, off, 64);
            if (j == 0) logits[kk] = contrib + c2[0];
        }
    }
    __syncthreads();
    if (t == 0) {
        float m = fmaxf(fmaxf(logits[0], logits[1]), fmaxf(logits[2], logits[3]));
        float e0 = expf(logits[0] - m), e1 = expf(logits[1] - m);
        float e2 = expf(logits[2] - m), e3 = expf(logits[3] - m);
        float s = e0 + e1 + e2 + e3;
        out[0] = e0 / s; out[1] = e1 / s; out[2] = e2 / s; out[3] = e3 / s;
    }
}

extern "C" void kernel_launch(void* const* d_in, const int* in_sizes, int n_in,
                              void* d_out, int out_size, void* d_ws, size_t ws_size,
                              hipStream_t stream) {
    const float* x      = (const float*)d_in[0];
    const int*   ei     = (const int*)d_in[1];
    const float* eattr  = (const float*)d_in[2];
    const int*   assign = (const int*)d_in[3];
    const float* W1     = (const float*)d_in[4];
    const float* as1    = (const float*)d_in[5];
    const float* ad1    = (const float*)d_in[6];
    const float* We1    = (const float*)d_in[7];
    const float* ae1    = (const float*)d_in[8];
    const float* b1     = (const float*)d_in[9];
    const float* W2     = (const float*)d_in[10];
    const float* as2    = (const float*)d_in[11];
    const float* ad2    = (const float*)d_in[12];
    const float* We2    = (const float*)d_in[13];
    const float* ae2    = (const float*)d_in[14];
    const float* b2     = (const float*)d_in[15];
    const float* A1     = (const float*)d_in[16];
    const float* c1     = (const float*)d_in[17];
    const float* A2     = (const float*)d_in[18];
    const float* c2     = (const float*)d_in[19];
    float* out = (float*)d_out;

    const int N_ = in_sizes[0] / 7;            // 50000
    const int E_ = in_sizes[2];                // 800000
    const int NB = (N_ + 255) / 256;
    const int BW = (N_ + NBUCK - 1) / NBUCK;   // 196 rows per bucket
    const int* srcA = ei;
    const int* dstA = ei + E_;

    // ---- workspace layout ----
    float* ws = (float*)d_ws;
    size_t Nz = (size_t)N_;
    float* al_s1   = ws;                       // 4N
    float* al_d1   = al_s1 + 4 * Nz;           // 4N
    float* al_s2   = al_d1 + 4 * Nz;           // N
    float* al_d2   = al_s2 + Nz;               // N
    float* ce1     = al_d2 + Nz;               // 4
    float* ce2     = ce1 + 4;                  // 4 (padded)
    float* zsum    = ce2 + 4;                  // 256
    float* cntK    = zsum + 256;               // 4
    float* cfK     = cntK + 4;                 // 4
    float* u_s     = cfK + 4;                  // 256
    float* u_d     = u_s + 256;                // 256
    float* xpad    = ws + 10 * Nz + 1024;      // 8N
    float* xacc    = xpad + 8 * Nz;            // 32N
    float* xw2     = xacc + 32 * Nz;           // 64N
    uintptr_t pp   = (uintptr_t)(xw2 + 64 * Nz);
    u64* gbuck     = (u64*)((pp + 7) & ~(uintptr_t)7);       // NBUCK*BCAP u64 (8 MB)
    u64* gpacked   = gbuck + (size_t)NBUCK * BCAP;           // NBUCK*BCAP u64 (8 MB)
    unsigned int* gtail = (unsigned int*)(gpacked + (size_t)NBUCK * BCAP);  // 256
    int2* idx2     = (int2*)(gtail + 256);                   // N int2
    unsigned short* W2T = (unsigned short*)(idx2 + Nz);      // 64*256 bf16

    // ---- zero the tiny accumulators ----
    hipMemsetAsync(zsum, 0, 264 * sizeof(float), stream);
    hipMemsetAsync(gtail, 0, NBUCK * sizeof(unsigned int), stream);

    // ---- constants + transpose + node prep (one dispatch) ----
    k_prep_all<<<NB, 256, 0, stream>>>(x, W1, W2, as1, ad1, as2, ad2,
                                       We1, ae1, We2, ae2,
                                       ce1, ce2, u_s, u_d, W2T,
                                       xpad, al_s1, al_d1, N_);

    // ---- two-pass binned CSR build (line-dense writes) ----
    k_bin<<<(E_ + 256 * EPT - 1) / (256 * EPT), 256, 0, stream>>>(srcA, dstA, eattr, gtail, gbuck, E_, BW);
    k_scatter2<<<NBUCK, 256, 0, stream>>>(gtail, gbuck, gpacked, idx2, N_, BW);

    // ---- conv1 ----
    k_agg1f<<<(4 * N_ + 255) / 256, 256, 0, stream>>>(idx2, gpacked, al_s1, al_d1, ce1, xpad, xacc, N_);

    // ---- conv2: MFMA h1-gen + GEMM, then fused softmax-aggregate + pooling ----
    k_xw2g<<<(N_ + 15) / 16, 256, 0, stream>>>(xacc, W1, b1, W2T, u_s, u_d,
                                               xw2, al_s2, al_d2, N_);
    k_agg2p<<<1024, 256, 0, stream>>>(idx2, gpacked, al_s2, al_d2, ce2, xw2,
                                      x, assign, zsum, cntK, cfK, N_);

    // ---- head ----
    k_head<<<1, 256, 0, stream>>>(zsum, cntK, cfK, b2, A1, c1, A2, c2, out);
}

// Round 14
// 262.836 us; speedup vs baseline: 1.0877x; 1.0877x over previous
//
#include <hip/hip_runtime.h>
#include <hip/hip_bf16.h>

#define HEADS 4
#define KCL 4
#define NBUCK 256
#define BCAP 4096            // bucket capacity (mean 3125, +17 sigma)
#define EPT 8                // edges per thread in k_bin
typedef unsigned long long u64;
typedef short short8 __attribute__((ext_vector_type(8)));
typedef float f32x4 __attribute__((ext_vector_type(4)));

__device__ __forceinline__ unsigned short bf16_rne(float f) {
    unsigned int u = __float_as_uint(f);
    u += 0x7FFFu + ((u >> 16) & 1u);
    return (unsigned short)(u >> 16);
}

// packed edge: [ea:32][dstlo:8][src:24]

// ---------------------------------------------------------------- k_bin: pass 1 — coarse-bucket append
__global__ __launch_bounds__(256) void k_bin(const int* __restrict__ src, const int* __restrict__ dst,
                                             const float* __restrict__ ea,
                                             unsigned int* __restrict__ gtail,
                                             u64* __restrict__ gbuck, int E_, int BW) {
    __shared__ unsigned int cnt[NBUCK];
    __shared__ unsigned int gb[NBUCK];
    int t = threadIdx.x;
    cnt[t] = 0u;
    __syncthreads();
    int e0 = blockIdx.x * (256 * EPT) + t;
    u64 pk[EPT]; int bk[EPT]; unsigned int ls[EPT];
    int m = 0;
#pragma unroll
    for (int i = 0; i < EPT; i++) {
        int e = e0 + i * 256;
        if (e < E_) {
            int s = src[e], d = dst[e];
            float a = ea[e];
            int b = d / BW;
            int lo = d - b * BW;
            pk[m] = ((u64)__float_as_uint(a) << 32) | ((u64)(unsigned int)lo << 24) | (unsigned int)s;
            bk[m] = b;
            ls[m] = atomicAdd(&cnt[b], 1u);
            m++;
        }
    }
    __syncthreads();
    gb[t] = (cnt[t] > 0u) ? atomicAdd(&gtail[t], cnt[t]) : 0u;
    __syncthreads();
    for (int i = 0; i < m; i++) {
        unsigned int pos = gb[bk[i]] + ls[i];
        if (pos < BCAP) gbuck[(size_t)bk[i] * BCAP + pos] = pk[i];
    }
}

// ---------------------------------------------------------------- k_scatter2: pass 2 — row-pack within bucket
__global__ __launch_bounds__(256) void k_scatter2(const unsigned int* __restrict__ gtail,
                                                  const u64* __restrict__ gbuck,
                                                  u64* __restrict__ gpacked,
                                                  int2* __restrict__ idx2, int N_, int BW) {
    __shared__ unsigned int rcnt[256], pre[256], cur[256];
    int b = blockIdx.x, t = threadIdx.x;
    unsigned int n = gtail[b]; if (n > BCAP) n = BCAP;
    int r0 = b * BW;
    rcnt[t] = 0u;
    __syncthreads();
    size_t base = (size_t)b * BCAP;
    for (unsigned int pos = t; pos < n; pos += 256) {
        u64 p = gbuck[base + pos];
        int lo = (int)((p >> 24) & 0xFFu);
        atomicAdd(&rcnt[lo], 1u);
    }
    __syncthreads();
    unsigned int v = rcnt[t];
    pre[t] = v;
    __syncthreads();
    for (int off = 1; off < 256; off <<= 1) {
        unsigned int u = (t >= off) ? pre[t - off] : 0u;
        __syncthreads();
        pre[t] += u;
        __syncthreads();
    }
    unsigned int excl = pre[t] - v;
    cur[t] = excl;
    if (t < BW && r0 + t < N_) idx2[r0 + t] = make_int2((int)(base + excl), (int)v);
    __syncthreads();
    for (unsigned int pos = t; pos < n; pos += 256) {
        u64 p = gbuck[base + pos];
        int lo = (int)((p >> 24) & 0xFFu);
        unsigned int slot = atomicAdd(&cur[lo], 1u);
        gpacked[base + slot] = p;
    }
}

// ---------------------------------------------------------------- k_prep_all: ce + u + W2T + per-node prep, one dispatch
__global__ __launch_bounds__(256) void k_prep_all(const float* __restrict__ x,
                                                  const float* __restrict__ W1, const float* __restrict__ W2,
                                                  const float* __restrict__ as1, const float* __restrict__ ad1,
                                                  const float* __restrict__ as2, const float* __restrict__ ad2,
                                                  const float* __restrict__ We1, const float* __restrict__ ae1,
                                                  const float* __restrict__ We2, const float* __restrict__ ae2,
                                                  float* __restrict__ ce1, float* __restrict__ ce2,
                                                  float* __restrict__ u_s, float* __restrict__ u_d,
                                                  unsigned short* __restrict__ W2T,
                                                  float* __restrict__ xpad,
                                                  float* __restrict__ al_s1, float* __restrict__ al_d1, int N_) {
    __shared__ float Ps_l[7][4], Pd_l[7][4];
    int t = threadIdx.x, h = t >> 6, lane = t & 63;
    for (int i = 0; i < 7; i++) {
        float a = W1[i * 256 + t];             // t = h*64+c
        float ps = a * as1[t];
        float pd = a * ad1[t];
        for (int off = 32; off; off >>= 1) {
            ps += __shfl_down(ps, off, 64);
            pd += __shfl_down(pd, off, 64);
        }
        if (lane == 0) { Ps_l[i][h] = ps; Pd_l[i][h] = pd; }
    }
    if (blockIdx.x == 0) {
        float p = We1[t] * ae1[t];
        for (int off = 32; off; off >>= 1) p += __shfl_down(p, off, 64);
        if (lane == 0) ce1[h] = p;
        if (t < 64) {
            float q = We2[t] * ae2[t];
            for (int off = 32; off; off >>= 1) q += __shfl_down(q, off, 64);
            if (t == 0) ce2[0] = q;
        }
        float us = 0.f, ud = 0.f;
        const float* wr = W2 + t * 64;
        for (int n = 0; n < 64; n++) { us += wr[n] * as2[n]; ud += wr[n] * ad2[n]; }
        u_s[t] = us; u_d[t] = ud;
    }
    int gidx = blockIdx.x * 256 + t;
    if (gidx < 16384) {
        int nn = gidx & 63, k = gidx >> 6;
        W2T[nn * 256 + k] = bf16_rne(W2[k * 64 + nn]);
    }
    __syncthreads();
    int n = gidx;
    if (n >= N_) return;
    float xv[7];
#pragma unroll
    for (int i = 0; i < 7; i++) xv[i] = x[n * 7 + i];
    ((float4*)(xpad + (size_t)n * 8))[0] = make_float4(xv[0], xv[1], xv[2], xv[3]);
    ((float4*)(xpad + (size_t)n * 8))[1] = make_float4(xv[4], xv[5], xv[6], 0.0f);
    float4 als = make_float4(0.f, 0.f, 0.f, 0.f);
    float4 ald = make_float4(0.f, 0.f, 0.f, 0.f);
#pragma unroll
    for (int i = 0; i < 7; i++) {
        als.x += xv[i] * Ps_l[i][0]; als.y += xv[i] * Ps_l[i][1];
        als.z += xv[i] * Ps_l[i][2]; als.w += xv[i] * Ps_l[i][3];
        ald.x += xv[i] * Pd_l[i][0]; ald.y += xv[i] * Pd_l[i][1];
        ald.z += xv[i] * Pd_l[i][2]; ald.w += xv[i] * Pd_l[i][3];
    }
    ((float4*)al_s1)[n] = als;
    ((float4*)al_d1)[n] = ald;
}

// ---------------------------------------------------------------- k_agg1f: fused edge-softmax + aggregation (conv1)
__global__ __launch_bounds__(256) void k_agg1f(const int2* __restrict__ idx2,
                                               const u64* __restrict__ gpacked,
                                               const float* __restrict__ al_s1,
                                               const float* __restrict__ al_d1,
                                               const float* __restrict__ ce1,
                                               const float* __restrict__ xpad,
                                               float* __restrict__ xacc, int N_) {
    int tid = blockIdx.x * 256 + threadIdx.x;
    int d = tid >> 2, h = tid & 3;
    if (d >= N_) return;
    int2 ix = idx2[d];
    const u64* row = gpacked + ix.x;
    int cnt = ix.y;
    float ald = al_d1[d * 4 + h];
    float ce = ce1[h];
    float4 accA = make_float4(0.f, 0.f, 0.f, 0.f);
    float4 accB = make_float4(0.f, 0.f, 0.f, 0.f);   // .w = wsum
    float easum = 0.0f;
    int j = 0;
    for (; j + 1 < cnt; j += 2) {
        u64 p0 = row[j], p1 = row[j + 1];
        int s0 = (int)(p0 & 0xFFFFFFu), s1 = (int)(p1 & 0xFFFFFFu);
        float a0 = __uint_as_float((unsigned int)(p0 >> 32));
        float a1 = __uint_as_float((unsigned int)(p1 >> 32));
        easum += a0 + a1;
        float v0 = al_s1[s0 * 4 + h] + ald + a0 * ce;
        float v1 = al_s1[s1 * 4 + h] + ald + a1 * ce;
        v0 = v0 > 0.f ? v0 : 0.2f * v0;
        v1 = v1 > 0.f ? v1 : 0.2f * v1;
        float w0 = __expf(v0), w1 = __expf(v1);
        float4 xa0 = ((const float4*)(xpad + (size_t)s0 * 8))[0];
        float4 xb0 = ((const float4*)(xpad + (size_t)s0 * 8))[1];
        float4 xa1 = ((const float4*)(xpad + (size_t)s1 * 8))[0];
        float4 xb1 = ((const float4*)(xpad + (size_t)s1 * 8))[1];
        accA.x += w0 * xa0.x + w1 * xa1.x;
        accA.y += w0 * xa0.y + w1 * xa1.y;
        accA.z += w0 * xa0.z + w1 * xa1.z;
        accA.w += w0 * xa0.w + w1 * xa1.w;
        accB.x += w0 * xb0.x + w1 * xb1.x;
        accB.y += w0 * xb0.y + w1 * xb1.y;
        accB.z += w0 * xb0.z + w1 * xb1.z;
        accB.w += w0 + w1;
    }
    if (j < cnt) {
        u64 p0 = row[j];
        int s0 = (int)(p0 & 0xFFFFFFu);
        float a0 = __uint_as_float((unsigned int)(p0 >> 32));
        easum += a0;
        float v0 = al_s1[s0 * 4 + h] + ald + a0 * ce;
        v0 = v0 > 0.f ? v0 : 0.2f * v0;
        float w0 = __expf(v0);
        float4 xa0 = ((const float4*)(xpad + (size_t)s0 * 8))[0];
        float4 xb0 = ((const float4*)(xpad + (size_t)s0 * 8))[1];
        accA.x += w0 * xa0.x; accA.y += w0 * xa0.y; accA.z += w0 * xa0.z; accA.w += w0 * xa0.w;
        accB.x += w0 * xb0.x; accB.y += w0 * xb0.y; accB.z += w0 * xb0.z;
        accB.w += w0;
    }
    // self-loop: attr = mean of real incoming ea
    {
        float a_self = easum / fmaxf((float)cnt, 1.0f);
        float v = al_s1[d * 4 + h] + ald + a_self * ce;
        v = v > 0.f ? v : 0.2f * v;
        float w = __expf(v);
        float4 xa0 = ((const float4*)(xpad + (size_t)d * 8))[0];
        float4 xb0 = ((const float4*)(xpad + (size_t)d * 8))[1];
        accA.x += w * xa0.x; accA.y += w * xa0.y; accA.z += w * xa0.z; accA.w += w * xa0.w;
        accB.x += w * xb0.x; accB.y += w * xb0.y; accB.z += w * xb0.z;
        accB.w += w;
    }
    float* o = xacc + (size_t)d * 32 + h * 8;
    ((float4*)o)[0] = accA;
    ((float4*)o)[1] = accB;
}

// ---------------------------------------------------------------- k_xw2g: MFMA version, lane-coalesced generation
__global__ __launch_bounds__(256) void k_xw2g(const float* __restrict__ xacc,
                                              const float* __restrict__ W1,
                                              const float* __restrict__ b1,
                                              const unsigned short* __restrict__ W2T,
                                              const float* __restrict__ u_s,
                                              const float* __restrict__ u_d,
                                              float* __restrict__ xw2,
                                              float* __restrict__ al_s2,
                                              float* __restrict__ al_d2, int N_) {
    __shared__ float Xs[16][32];
    __shared__ __align__(16) unsigned short A_lds[16][264];  // k-pad +8 breaks bank alias
    __shared__ float als_p[16], ald_p[16];
    int t = threadIdx.x;
    int m0 = blockIdx.x * 16;
    if (t < 128) {
        int r = t >> 3, off = (t & 7) * 4;
        int n = m0 + r;
        float4 v = (n < N_) ? *(const float4*)(xacc + (size_t)n * 32 + off)
                            : make_float4(0.f, 0.f, 0.f, 0.f);
        *(float4*)&Xs[r][off] = v;
    }
    __syncthreads();
    // generation: row r = t>>4, lane-k kk = t&15
    {
        int r = t >> 4;
        int kk = t & 15;
        float ps = 0.f, pd = 0.f;
#pragma unroll
        for (int h = 0; h < 4; h++) {
            float xv[7];
#pragma unroll
            for (int i = 0; i < 7; i++) xv[i] = Xs[r][h * 8 + i];
            float rw = 1.0f / (Xs[r][h * 8 + 7] + 1e-16f);
#pragma unroll
            for (int q2 = 0; q2 < 4; q2++) {
                int k = h * 64 + q2 * 16 + kk;
                float s = 0.f;
#pragma unroll
                for (int i = 0; i < 7; i++) s += xv[i] * W1[i * 256 + k];
                float v = s * rw + b1[k];
                float a = v > 0.f ? v : (__expf(v) - 1.0f);
                ps += a * u_s[k];
                pd += a * u_d[k];
                A_lds[r][k] = bf16_rne(a);
            }
        }
#pragma unroll
        for (int mdel = 1; mdel < 16; mdel <<= 1) {
            ps += __shfl_xor(ps, mdel, 64);
            pd += __shfl_xor(pd, mdel, 64);
        }
        if (kk == 0) { als_p[r] = ps; ald_p[r] = pd; }
    }
    __syncthreads();
    // MFMA: wave w covers cols w*16..w*16+15
    int w = t >> 6, lane = t & 63;
    int mm = lane & 15, quad = lane >> 4;
    int n0 = w * 16;
    f32x4 acc = {0.f, 0.f, 0.f, 0.f};
    const unsigned short* bptr = W2T + (size_t)(n0 + mm) * 256;
#pragma unroll
    for (int step = 0; step < 8; step++) {
        int kf = step * 32 + quad * 8;
        short8 af = *(const short8*)&A_lds[mm][kf];
        short8 bf = *(const short8*)&bptr[kf];
        acc = __builtin_amdgcn_mfma_f32_16x16x32_bf16(af, bf, acc, 0, 0, 0);
    }
#pragma unroll
    for (int r = 0; r < 4; r++) {
        int row = m0 + quad * 4 + r;
        if (row < N_) xw2[(size_t)row * 64 + n0 + mm] = acc[r];
    }
    if (t < 16 && m0 + t < N_) { al_s2[m0 + t] = als_p[t]; al_d2[m0 + t] = ald_p[t]; }
}

// ---------------------------------------------------------------- k_agg2f: conv2 softmax-aggregate, lane-parallel weights
// one wave per dst (12500 blocks x 4 waves) — max wave count for latency hiding
__global__ __launch_bounds__(256) void k_agg2f(const int2* __restrict__ idx2,
                                               const u64* __restrict__ gpacked,
                                               const float* __restrict__ al_s2,
                                               const float* __restrict__ al_d2,
                                               const float* __restrict__ ce2,
                                               const float* __restrict__ xw2,
                                               float* __restrict__ h2, int N_) {
    int wid = threadIdx.x >> 6, lane = threadIdx.x & 63;
    int d = blockIdx.x * 4 + wid;
    if (d >= N_) return;
    int2 ix = idx2[d];
    const u64* row = gpacked + ix.x;
    int cnt = ix.y;
    float ald = al_d2[d];
    float ce = ce2[0];
    float acc = 0.0f;
    float wlane = 0.0f, alane = 0.0f;
    for (int pos = 0; pos < cnt; pos += 64) {
        int nle = min(64, cnt - pos);
        float w = 0.0f, a = 0.0f;
        int s = d;
        if (lane < nle) {
            u64 p = row[pos + lane];
            s = (int)(p & 0xFFFFFFu);
            a = __uint_as_float((unsigned int)(p >> 32));
            float v = al_s2[s] + ald + a * ce;
            v = v > 0.f ? v : 0.2f * v;
            w = __expf(v);
        }
        wlane += w;
        alane += a;
        int jj = 0;
        for (; jj + 1 < nle; jj += 2) {
            float wj0 = __uint_as_float(__builtin_amdgcn_readlane(__float_as_uint(w), jj));
            int   sj0 = __builtin_amdgcn_readlane(s, jj);
            float wj1 = __uint_as_float(__builtin_amdgcn_readlane(__float_as_uint(w), jj + 1));
            int   sj1 = __builtin_amdgcn_readlane(s, jj + 1);
            acc += wj0 * xw2[(size_t)sj0 * 64 + lane] + wj1 * xw2[(size_t)sj1 * 64 + lane];
        }
        if (jj < nle) {
            float wj = __uint_as_float(__builtin_amdgcn_readlane(__float_as_uint(w), jj));
            int   sj = __builtin_amdgcn_readlane(s, jj);
            acc += wj * xw2[(size_t)sj * 64 + lane];
        }
    }
    float wsum = wlane, easum = alane;
    for (int off = 32; off; off >>= 1) {
        wsum += __shfl_xor(wsum, off, 64);
        easum += __shfl_xor(easum, off, 64);
    }
    float a_self = easum / fmaxf((float)cnt, 1.0f);
    float v = al_s2[d] + ald + a_self * ce;
    v = v > 0.f ? v : 0.2f * v;
    float w = __expf(v);
    acc += w * xw2[(size_t)d * 64 + lane];
    wsum += w;
    h2[(size_t)d * 64 + lane] = acc / (wsum + 1e-16f);
}

// ---------------------------------------------------------------- k_pool: cluster pooling (LDS partials, 256 blocks)
__global__ __launch_bounds__(256) void k_pool(const float* __restrict__ h2, const float* __restrict__ x,
                                              const int* __restrict__ assign,
                                              float* __restrict__ zsum, float* __restrict__ cntK,
                                              float* __restrict__ cfK, int nNodes) {
    __shared__ float lz[KCL * 64];
    __shared__ float lc[KCL];
    __shared__ float lf[KCL];
    int t = threadIdx.x;
    lz[t] = 0.0f;
    if (t < KCL) { lc[t] = 0.0f; lf[t] = 0.0f; }
    __syncthreads();
    int lane = t & 63, wid = t >> 6;
    for (int n = blockIdx.x * 4 + wid; n < nNodes; n += gridDim.x * 4) {
        int a = assign[n];
        atomicAdd(&lz[a * 64 + lane], h2[(size_t)n * 64 + lane]);
        if (lane == 0) {
            atomicAdd(&lc[a], 1.0f);
            atomicAdd(&lf[a], x[n * 7 + 6]);
        }
    }
    __syncthreads();
    atomicAdd(&zsum[t], lz[t]);
    if (t < KCL) {
        atomicAdd(&cntK[t], lc[t]);
        atomicAdd(&cfK[t], lf[t]);
    }
}

// ---------------------------------------------------------------- k_head: actor head + outputs
__global__ __launch_bounds__(256) void k_head(const float* __restrict__ zsum, const float* __restrict__ cntK,
                                              const float* __restrict__ cfK, const float* __restrict__ b2,
                                              const float* __restrict__ A1, const float* __restrict__ c1,
                                              const float* __restrict__ A2, const float* __restrict__ c2,
                                              float* __restrict__ out) {
    __shared__ float zcf[KCL][65];
    __shared__ float logits[KCL];
    int t = threadIdx.x;                       // 256
    int k = t >> 6, c = t & 63;
    float cn = cntK[k];
    float z = (cn > 0.f) ? (zsum[k * 64 + c] / fmaxf(cn, 1.0f) + b2[c]) : 0.0f;
    zcf[k][c] = z;
    out[4 + k * 64 + c] = z;                   // z_flat
    if (c == 0) zcf[k][64] = (cn > 0.f) ? (cfK[k] / fmaxf(cn, 1.0f)) : 0.0f;
    __syncthreads();
    if (t < 64) {
        int j = t;
#pragma unroll
        for (int kk = 0; kk < KCL; kk++) {
            float acc = 0.0f;
            for (int i = 0; i < 65; i++) acc += zcf[kk][i] * A1[i * 64 + j];
            float hr = fmaxf(acc + c1[j], 0.0f);
            float contrib = hr * A2[j];
            for (int off = 32; off; off >>= 1) contrib += __shfl_down(contrib, off, 64);
            if (j == 0) logits[kk] = contrib + c2[0];
        }
    }
    __syncthreads();
    if (t == 0) {
        float m = fmaxf(fmaxf(logits[0], logits[1]), fmaxf(logits[2], logits[3]));
        float e0 = expf(logits[0] - m), e1 = expf(logits[1] - m);
        float e2 = expf(logits[2] - m), e3 = expf(logits[3] - m);
        float s = e0 + e1 + e2 + e3;
        out[0] = e0 / s; out[1] = e1 / s; out[2] = e2 / s; out[3] = e3 / s;
    }
}

extern "C" void kernel_launch(void* const* d_in, const int* in_sizes, int n_in,
                              void* d_out, int out_size, void* d_ws, size_t ws_size,
                              hipStream_t stream) {
    const float* x      = (const float*)d_in[0];
    const int*   ei     = (const int*)d_in[1];
    const float* eattr  = (const float*)d_in[2];
    const int*   assign = (const int*)d_in[3];
    const float* W1     = (const float*)d_in[4];
    const float* as1    = (const float*)d_in[5];
    const float* ad1    = (const float*)d_in[6];
    const float* We1    = (const float*)d_in[7];
    const float* ae1    = (const float*)d_in[8];
    const float* b1     = (const float*)d_in[9];
    const float* W2     = (const float*)d_in[10];
    const float* as2    = (const float*)d_in[11];
    const float* ad2    = (const float*)d_in[12];
    const float* We2    = (const float*)d_in[13];
    const float* ae2    = (const float*)d_in[14];
    const float* b2     = (const float*)d_in[15];
    const float* A1     = (const float*)d_in[16];
    const float* c1     = (const float*)d_in[17];
    const float* A2     = (const float*)d_in[18];
    const float* c2     = (const float*)d_in[19];
    float* out = (float*)d_out;

    const int N_ = in_sizes[0] / 7;            // 50000
    const int E_ = in_sizes[2];                // 800000
    const int NB = (N_ + 255) / 256;
    const int BW = (N_ + NBUCK - 1) / NBUCK;   // 196 rows per bucket
    const int* srcA = ei;
    const int* dstA = ei + E_;

    // ---- workspace layout ----
    float* ws = (float*)d_ws;
    size_t Nz = (size_t)N_;
    float* al_s1   = ws;                       // 4N
    float* al_d1   = al_s1 + 4 * Nz;           // 4N
    float* al_s2   = al_d1 + 4 * Nz;           // N
    float* al_d2   = al_s2 + Nz;               // N
    float* ce1     = al_d2 + Nz;               // 4
    float* ce2     = ce1 + 4;                  // 4 (padded)
    float* zsum    = ce2 + 4;                  // 256
    float* cntK    = zsum + 256;               // 4
    float* cfK     = cntK + 4;                 // 4
    float* u_s     = cfK + 4;                  // 256
    float* u_d     = u_s + 256;                // 256
    float* xpad    = ws + 10 * Nz + 1024;      // 8N
    float* xacc    = xpad + 8 * Nz;            // 32N
    float* xw2     = xacc + 32 * Nz;           // 64N
    float* h2      = xw2 + 64 * Nz;            // 64N
    uintptr_t pp   = (uintptr_t)(h2 + 64 * Nz);
    u64* gbuck     = (u64*)((pp + 7) & ~(uintptr_t)7);       // NBUCK*BCAP u64 (8 MB)
    u64* gpacked   = gbuck + (size_t)NBUCK * BCAP;           // NBUCK*BCAP u64 (8 MB)
    unsigned int* gtail = (unsigned int*)(gpacked + (size_t)NBUCK * BCAP);  // 256
    int2* idx2     = (int2*)(gtail + 256);                   // N int2
    unsigned short* W2T = (unsigned short*)(idx2 + Nz);      // 64*256 bf16

    // ---- zero the tiny accumulators ----
    hipMemsetAsync(zsum, 0, 264 * sizeof(float), stream);
    hipMemsetAsync(gtail, 0, NBUCK * sizeof(unsigned int), stream);

    // ---- constants + transpose + node prep (one dispatch) ----
    k_prep_all<<<NB, 256, 0, stream>>>(x, W1, W2, as1, ad1, as2, ad2,
                                       We1, ae1, We2, ae2,
                                       ce1, ce2, u_s, u_d, W2T,
                                       xpad, al_s1, al_d1, N_);

    // ---- two-pass binned CSR build (line-dense writes) ----
    k_bin<<<(E_ + 256 * EPT - 1) / (256 * EPT), 256, 0, stream>>>(srcA, dstA, eattr, gtail, gbuck, E_, BW);
    k_scatter2<<<NBUCK, 256, 0, stream>>>(gtail, gbuck, gpacked, idx2, N_, BW);

    // ---- conv1 ----
    k_agg1f<<<(4 * N_ + 255) / 256, 256, 0, stream>>>(idx2, gpacked, al_s1, al_d1, ce1, xpad, xacc, N_);

    // ---- conv2: MFMA h1-gen + GEMM, then softmax-aggregate (1 wave/dst), then pooling ----
    k_xw2g<<<(N_ + 15) / 16, 256, 0, stream>>>(xacc, W1, b1, W2T, u_s, u_d,
                                               xw2, al_s2, al_d2, N_);
    k_agg2f<<<(N_ + 3) / 4, 256, 0, stream>>>(idx2, gpacked, al_s2, al_d2, ce2, xw2, h2, N_);
    k_pool<<<256, 256, 0, stream>>>(h2, x, assign, zsum, cntK, cfK, N_);

    // ---- head ----
    k_head<<<1, 256, 0, stream>>>(zsum, cntK, cfK, b2, A1, c1, A2, c2, out);
}

// Round 15
// 262.605 us; speedup vs baseline: 1.0886x; 1.0009x over previous
//
#include <hip/hip_runtime.h>
#include <hip/hip_bf16.h>

#define HEADS 4
#define KCL 4
#define NBUCK 256
#define BCAP 4096            // bucket capacity (mean 3125, +17 sigma)
#define EPT 8                // edges per thread in k_bin
typedef unsigned long long u64;
typedef short short8 __attribute__((ext_vector_type(8)));
typedef float f32x4 __attribute__((ext_vector_type(4)));

__device__ __forceinline__ unsigned short bf16_rne(float f) {
    unsigned int u = __float_as_uint(f);
    u += 0x7FFFu + ((u >> 16) & 1u);
    return (unsigned short)(u >> 16);
}
__device__ __forceinline__ float bf16_to_f32(unsigned short h) {
    return __uint_as_float(((unsigned int)h) << 16);
}

// packed edge: [ea:32][dstlo:8][src:24]

// ---------------------------------------------------------------- k_bin: pass 1 — coarse-bucket append
__global__ __launch_bounds__(256) void k_bin(const int* __restrict__ src, const int* __restrict__ dst,
                                             const float* __restrict__ ea,
                                             unsigned int* __restrict__ gtail,
                                             u64* __restrict__ gbuck, int E_, int BW) {
    __shared__ unsigned int cnt[NBUCK];
    __shared__ unsigned int gb[NBUCK];
    int t = threadIdx.x;
    cnt[t] = 0u;
    __syncthreads();
    int e0 = blockIdx.x * (256 * EPT) + t;
    u64 pk[EPT]; int bk[EPT]; unsigned int ls[EPT];
    int m = 0;
#pragma unroll
    for (int i = 0; i < EPT; i++) {
        int e = e0 + i * 256;
        if (e < E_) {
            int s = src[e], d = dst[e];
            float a = ea[e];
            int b = d / BW;
            int lo = d - b * BW;
            pk[m] = ((u64)__float_as_uint(a) << 32) | ((u64)(unsigned int)lo << 24) | (unsigned int)s;
            bk[m] = b;
            ls[m] = atomicAdd(&cnt[b], 1u);
            m++;
        }
    }
    __syncthreads();
    gb[t] = (cnt[t] > 0u) ? atomicAdd(&gtail[t], cnt[t]) : 0u;
    __syncthreads();
    for (int i = 0; i < m; i++) {
        unsigned int pos = gb[bk[i]] + ls[i];
        if (pos < BCAP) gbuck[(size_t)bk[i] * BCAP + pos] = pk[i];
    }
}

// ---------------------------------------------------------------- k_scatter2: pass 2 — row-pack within bucket
__global__ __launch_bounds__(256) void k_scatter2(const unsigned int* __restrict__ gtail,
                                                  const u64* __restrict__ gbuck,
                                                  u64* __restrict__ gpacked,
                                                  int2* __restrict__ idx2, int N_, int BW) {
    __shared__ unsigned int rcnt[256], pre[256], cur[256];
    int b = blockIdx.x, t = threadIdx.x;
    unsigned int n = gtail[b]; if (n > BCAP) n = BCAP;
    int r0 = b * BW;
    rcnt[t] = 0u;
    __syncthreads();
    size_t base = (size_t)b * BCAP;
    for (unsigned int pos = t; pos < n; pos += 256) {
        u64 p = gbuck[base + pos];
        int lo = (int)((p >> 24) & 0xFFu);
        atomicAdd(&rcnt[lo], 1u);
    }
    __syncthreads();
    unsigned int v = rcnt[t];
    pre[t] = v;
    __syncthreads();
    for (int off = 1; off < 256; off <<= 1) {
        unsigned int u = (t >= off) ? pre[t - off] : 0u;
        __syncthreads();
        pre[t] += u;
        __syncthreads();
    }
    unsigned int excl = pre[t] - v;
    cur[t] = excl;
    if (t < BW && r0 + t < N_) idx2[r0 + t] = make_int2((int)(base + excl), (int)v);
    __syncthreads();
    for (unsigned int pos = t; pos < n; pos += 256) {
        u64 p = gbuck[base + pos];
        int lo = (int)((p >> 24) & 0xFFu);
        unsigned int slot = atomicAdd(&cur[lo], 1u);
        gpacked[base + slot] = p;
    }
}

// ---------------------------------------------------------------- k_prep_all: ce + u + W2T + per-node prep, one dispatch
__global__ __launch_bounds__(256) void k_prep_all(const float* __restrict__ x,
                                                  const float* __restrict__ W1, const float* __restrict__ W2,
                                                  const float* __restrict__ as1, const float* __restrict__ ad1,
                                                  const float* __restrict__ as2, const float* __restrict__ ad2,
                                                  const float* __restrict__ We1, const float* __restrict__ ae1,
                                                  const float* __restrict__ We2, const float* __restrict__ ae2,
                                                  float* __restrict__ ce1, float* __restrict__ ce2,
                                                  float* __restrict__ u_s, float* __restrict__ u_d,
                                                  unsigned short* __restrict__ W2T,
                                                  float* __restrict__ xpad,
                                                  float* __restrict__ al_s1, float* __restrict__ al_d1, int N_) {
    __shared__ float Ps_l[7][4], Pd_l[7][4];
    int t = threadIdx.x, h = t >> 6, lane = t & 63;
    for (int i = 0; i < 7; i++) {
        float a = W1[i * 256 + t];             // t = h*64+c
        float ps = a * as1[t];
        float pd = a * ad1[t];
        for (int off = 32; off; off >>= 1) {
            ps += __shfl_down(ps, off, 64);
            pd += __shfl_down(pd, off, 64);
        }
        if (lane == 0) { Ps_l[i][h] = ps; Pd_l[i][h] = pd; }
    }
    if (blockIdx.x == 0) {
        float p = We1[t] * ae1[t];
        for (int off = 32; off; off >>= 1) p += __shfl_down(p, off, 64);
        if (lane == 0) ce1[h] = p;
        if (t < 64) {
            float q = We2[t] * ae2[t];
            for (int off = 32; off; off >>= 1) q += __shfl_down(q, off, 64);
            if (t == 0) ce2[0] = q;
        }
        float us = 0.f, ud = 0.f;
        const float* wr = W2 + t * 64;
        for (int n = 0; n < 64; n++) { us += wr[n] * as2[n]; ud += wr[n] * ad2[n]; }
        u_s[t] = us; u_d[t] = ud;
    }
    int gidx = blockIdx.x * 256 + t;
    if (gidx < 16384) {
        int nn = gidx & 63, k = gidx >> 6;
        W2T[nn * 256 + k] = bf16_rne(W2[k * 64 + nn]);
    }
    __syncthreads();
    int n = gidx;
    if (n >= N_) return;
    float xv[7];
#pragma unroll
    for (int i = 0; i < 7; i++) xv[i] = x[n * 7 + i];
    ((float4*)(xpad + (size_t)n * 8))[0] = make_float4(xv[0], xv[1], xv[2], xv[3]);
    ((float4*)(xpad + (size_t)n * 8))[1] = make_float4(xv[4], xv[5], xv[6], 0.0f);
    float4 als = make_float4(0.f, 0.f, 0.f, 0.f);
    float4 ald = make_float4(0.f, 0.f, 0.f, 0.f);
#pragma unroll
    for (int i = 0; i < 7; i++) {
        als.x += xv[i] * Ps_l[i][0]; als.y += xv[i] * Ps_l[i][1];
        als.z += xv[i] * Ps_l[i][2]; als.w += xv[i] * Ps_l[i][3];
        ald.x += xv[i] * Pd_l[i][0]; ald.y += xv[i] * Pd_l[i][1];
        ald.z += xv[i] * Pd_l[i][2]; ald.w += xv[i] * Pd_l[i][3];
    }
    ((float4*)al_s1)[n] = als;
    ((float4*)al_d1)[n] = ald;
}

// ---------------------------------------------------------------- k_agg1f: fused edge-softmax + aggregation (conv1), 4-wide unroll
__global__ __launch_bounds__(256) void k_agg1f(const int2* __restrict__ idx2,
                                               const u64* __restrict__ gpacked,
                                               const float* __restrict__ al_s1,
                                               const float* __restrict__ al_d1,
                                               const float* __restrict__ ce1,
                                               const float* __restrict__ xpad,
                                               float* __restrict__ xacc, int N_) {
    int tid = blockIdx.x * 256 + threadIdx.x;
    int d = tid >> 2, h = tid & 3;
    if (d >= N_) return;
    int2 ix = idx2[d];
    const u64* row = gpacked + ix.x;
    int cnt = ix.y;
    float ald = al_d1[d * 4 + h];
    float ce = ce1[h];
    float4 accA = make_float4(0.f, 0.f, 0.f, 0.f);
    float4 accB = make_float4(0.f, 0.f, 0.f, 0.f);   // .w = wsum
    float easum = 0.0f;
    int j = 0;
    for (; j + 3 < cnt; j += 4) {
        u64 p0 = row[j], p1 = row[j + 1], p2 = row[j + 2], p3 = row[j + 3];
        int s0 = (int)(p0 & 0xFFFFFFu), s1 = (int)(p1 & 0xFFFFFFu);
        int s2 = (int)(p2 & 0xFFFFFFu), s3 = (int)(p3 & 0xFFFFFFu);
        float a0 = __uint_as_float((unsigned int)(p0 >> 32));
        float a1 = __uint_as_float((unsigned int)(p1 >> 32));
        float a2 = __uint_as_float((unsigned int)(p2 >> 32));
        float a3 = __uint_as_float((unsigned int)(p3 >> 32));
        easum += (a0 + a1) + (a2 + a3);
        float v0 = al_s1[s0 * 4 + h] + ald + a0 * ce;
        float v1 = al_s1[s1 * 4 + h] + ald + a1 * ce;
        float v2 = al_s1[s2 * 4 + h] + ald + a2 * ce;
        float v3 = al_s1[s3 * 4 + h] + ald + a3 * ce;
        v0 = v0 > 0.f ? v0 : 0.2f * v0;
        v1 = v1 > 0.f ? v1 : 0.2f * v1;
        v2 = v2 > 0.f ? v2 : 0.2f * v2;
        v3 = v3 > 0.f ? v3 : 0.2f * v3;
        float w0 = __expf(v0), w1 = __expf(v1), w2 = __expf(v2), w3 = __expf(v3);
        float4 xa0 = ((const float4*)(xpad + (size_t)s0 * 8))[0];
        float4 xb0 = ((const float4*)(xpad + (size_t)s0 * 8))[1];
        float4 xa1 = ((const float4*)(xpad + (size_t)s1 * 8))[0];
        float4 xb1 = ((const float4*)(xpad + (size_t)s1 * 8))[1];
        float4 xa2 = ((const float4*)(xpad + (size_t)s2 * 8))[0];
        float4 xb2 = ((const float4*)(xpad + (size_t)s2 * 8))[1];
        float4 xa3 = ((const float4*)(xpad + (size_t)s3 * 8))[0];
        float4 xb3 = ((const float4*)(xpad + (size_t)s3 * 8))[1];
        accA.x += (w0 * xa0.x + w1 * xa1.x) + (w2 * xa2.x + w3 * xa3.x);
        accA.y += (w0 * xa0.y + w1 * xa1.y) + (w2 * xa2.y + w3 * xa3.y);
        accA.z += (w0 * xa0.z + w1 * xa1.z) + (w2 * xa2.z + w3 * xa3.z);
        accA.w += (w0 * xa0.w + w1 * xa1.w) + (w2 * xa2.w + w3 * xa3.w);
        accB.x += (w0 * xb0.x + w1 * xb1.x) + (w2 * xb2.x + w3 * xb3.x);
        accB.y += (w0 * xb0.y + w1 * xb1.y) + (w2 * xb2.y + w3 * xb3.y);
        accB.z += (w0 * xb0.z + w1 * xb1.z) + (w2 * xb2.z + w3 * xb3.z);
        accB.w += (w0 + w1) + (w2 + w3);
    }
    for (; j < cnt; j++) {
        u64 p0 = row[j];
        int s0 = (int)(p0 & 0xFFFFFFu);
        float a0 = __uint_as_float((unsigned int)(p0 >> 32));
        easum += a0;
        float v0 = al_s1[s0 * 4 + h] + ald + a0 * ce;
        v0 = v0 > 0.f ? v0 : 0.2f * v0;
        float w0 = __expf(v0);
        float4 xa0 = ((const float4*)(xpad + (size_t)s0 * 8))[0];
        float4 xb0 = ((const float4*)(xpad + (size_t)s0 * 8))[1];
        accA.x += w0 * xa0.x; accA.y += w0 * xa0.y; accA.z += w0 * xa0.z; accA.w += w0 * xa0.w;
        accB.x += w0 * xb0.x; accB.y += w0 * xb0.y; accB.z += w0 * xb0.z;
        accB.w += w0;
    }
    // self-loop: attr = mean of real incoming ea
    {
        float a_self = easum / fmaxf((float)cnt, 1.0f);
        float v = al_s1[d * 4 + h] + ald + a_self * ce;
        v = v > 0.f ? v : 0.2f * v;
        float w = __expf(v);
        float4 xa0 = ((const float4*)(xpad + (size_t)d * 8))[0];
        float4 xb0 = ((const float4*)(xpad + (size_t)d * 8))[1];
        accA.x += w * xa0.x; accA.y += w * xa0.y; accA.z += w * xa0.z; accA.w += w * xa0.w;
        accB.x += w * xb0.x; accB.y += w * xb0.y; accB.z += w * xb0.z;
        accB.w += w;
    }
    float* o = xacc + (size_t)d * 32 + h * 8;
    ((float4*)o)[0] = accA;
    ((float4*)o)[1] = accB;
}

// ---------------------------------------------------------------- k_xw2g: MFMA h1-gen + GEMM; xw2 stored as bf16
__global__ __launch_bounds__(256) void k_xw2g(const float* __restrict__ xacc,
                                              const float* __restrict__ W1,
                                              const float* __restrict__ b1,
                                              const unsigned short* __restrict__ W2T,
                                              const float* __restrict__ u_s,
                                              const float* __restrict__ u_d,
                                              unsigned short* __restrict__ xw2b,
                                              float* __restrict__ al_s2,
                                              float* __restrict__ al_d2, int N_) {
    __shared__ float Xs[16][32];
    __shared__ __align__(16) unsigned short A_lds[16][264];  // k-pad +8 breaks bank alias
    __shared__ float als_p[16], ald_p[16];
    int t = threadIdx.x;
    int m0 = blockIdx.x * 16;
    if (t < 128) {
        int r = t >> 3, off = (t & 7) * 4;
        int n = m0 + r;
        float4 v = (n < N_) ? *(const float4*)(xacc + (size_t)n * 32 + off)
                            : make_float4(0.f, 0.f, 0.f, 0.f);
        *(float4*)&Xs[r][off] = v;
    }
    __syncthreads();
    // generation: row r = t>>4, lane-k kk = t&15 (lane-coalesced W1/u/b1 loads)
    {
        int r = t >> 4;
        int kk = t & 15;
        float ps = 0.f, pd = 0.f;
#pragma unroll
        for (int h = 0; h < 4; h++) {
            float xv[7];
#pragma unroll
            for (int i = 0; i < 7; i++) xv[i] = Xs[r][h * 8 + i];
            float rw = 1.0f / (Xs[r][h * 8 + 7] + 1e-16f);
#pragma unroll
            for (int q2 = 0; q2 < 4; q2++) {
                int k = h * 64 + q2 * 16 + kk;
                float s = 0.f;
#pragma unroll
                for (int i = 0; i < 7; i++) s += xv[i] * W1[i * 256 + k];
                float v = s * rw + b1[k];
                float a = v > 0.f ? v : (__expf(v) - 1.0f);
                ps += a * u_s[k];
                pd += a * u_d[k];
                A_lds[r][k] = bf16_rne(a);
            }
        }
#pragma unroll
        for (int mdel = 1; mdel < 16; mdel <<= 1) {
            ps += __shfl_xor(ps, mdel, 64);
            pd += __shfl_xor(pd, mdel, 64);
        }
        if (kk == 0) { als_p[r] = ps; ald_p[r] = pd; }
    }
    __syncthreads();
    // MFMA: wave w covers cols w*16..w*16+15
    int w = t >> 6, lane = t & 63;
    int mm = lane & 15, quad = lane >> 4;
    int n0 = w * 16;
    f32x4 acc = {0.f, 0.f, 0.f, 0.f};
    const unsigned short* bptr = W2T + (size_t)(n0 + mm) * 256;
#pragma unroll
    for (int step = 0; step < 8; step++) {
        int kf = step * 32 + quad * 8;
        short8 af = *(const short8*)&A_lds[mm][kf];
        short8 bf = *(const short8*)&bptr[kf];
        acc = __builtin_amdgcn_mfma_f32_16x16x32_bf16(af, bf, acc, 0, 0, 0);
    }
#pragma unroll
    for (int r = 0; r < 4; r++) {
        int row = m0 + quad * 4 + r;
        if (row < N_) xw2b[(size_t)row * 64 + n0 + mm] = bf16_rne(acc[r]);
    }
    if (t < 16 && m0 + t < N_) { al_s2[m0 + t] = als_p[t]; al_d2[m0 + t] = ald_p[t]; }
}

// ---------------------------------------------------------------- k_agg2f: conv2 softmax-aggregate, bf16 gathers
// one wave per dst (12500 blocks x 4 waves) — max wave count for latency hiding
__global__ __launch_bounds__(256) void k_agg2f(const int2* __restrict__ idx2,
                                               const u64* __restrict__ gpacked,
                                               const float* __restrict__ al_s2,
                                               const float* __restrict__ al_d2,
                                               const float* __restrict__ ce2,
                                               const unsigned short* __restrict__ xw2b,
                                               float* __restrict__ h2, int N_) {
    int wid = threadIdx.x >> 6, lane = threadIdx.x & 63;
    int d = blockIdx.x * 4 + wid;
    if (d >= N_) return;
    int2 ix = idx2[d];
    const u64* row = gpacked + ix.x;
    int cnt = ix.y;
    float ald = al_d2[d];
    float ce = ce2[0];
    float acc = 0.0f;
    float wlane = 0.0f, alane = 0.0f;
    for (int pos = 0; pos < cnt; pos += 64) {
        int nle = min(64, cnt - pos);
        float w = 0.0f, a = 0.0f;
        int s = d;
        if (lane < nle) {
            u64 p = row[pos + lane];
            s = (int)(p & 0xFFFFFFu);
            a = __uint_as_float((unsigned int)(p >> 32));
            float v = al_s2[s] + ald + a * ce;
            v = v > 0.f ? v : 0.2f * v;
            w = __expf(v);
        }
        wlane += w;
        alane += a;
        int jj = 0;
        for (; jj + 1 < nle; jj += 2) {
            float wj0 = __uint_as_float(__builtin_amdgcn_readlane(__float_as_uint(w), jj));
            int   sj0 = __builtin_amdgcn_readlane(s, jj);
            float wj1 = __uint_as_float(__builtin_amdgcn_readlane(__float_as_uint(w), jj + 1));
            int   sj1 = __builtin_amdgcn_readlane(s, jj + 1);
            acc += wj0 * bf16_to_f32(xw2b[(size_t)sj0 * 64 + lane])
                 + wj1 * bf16_to_f32(xw2b[(size_t)sj1 * 64 + lane]);
        }
        if (jj < nle) {
            float wj = __uint_as_float(__builtin_amdgcn_readlane(__float_as_uint(w), jj));
            int   sj = __builtin_amdgcn_readlane(s, jj);
            acc += wj * bf16_to_f32(xw2b[(size_t)sj * 64 + lane]);
        }
    }
    float wsum = wlane, easum = alane;
    for (int off = 32; off; off >>= 1) {
        wsum += __shfl_xor(wsum, off, 64);
        easum += __shfl_xor(easum, off, 64);
    }
    float a_self = easum / fmaxf((float)cnt, 1.0f);
    float v = al_s2[d] + ald + a_self * ce;
    v = v > 0.f ? v : 0.2f * v;
    float w = __expf(v);
    acc += w * bf16_to_f32(xw2b[(size_t)d * 64 + lane]);
    wsum += w;
    h2[(size_t)d * 64 + lane] = acc / (wsum + 1e-16f);
}

// ---------------------------------------------------------------- k_pool: cluster pooling (LDS partials, 256 blocks)
__global__ __launch_bounds__(256) void k_pool(const float* __restrict__ h2, const float* __restrict__ x,
                                              const int* __restrict__ assign,
                                              float* __restrict__ zsum, float* __restrict__ cntK,
                                              float* __restrict__ cfK, int nNodes) {
    __shared__ float lz[KCL * 64];
    __shared__ float lc[KCL];
    __shared__ float lf[KCL];
    int t = threadIdx.x;
    lz[t] = 0.0f;
    if (t < KCL) { lc[t] = 0.0f; lf[t] = 0.0f; }
    __syncthreads();
    int lane = t & 63, wid = t >> 6;
    for (int n = blockIdx.x * 4 + wid; n < nNodes; n += gridDim.x * 4) {
        int a = assign[n];
        atomicAdd(&lz[a * 64 + lane], h2[(size_t)n * 64 + lane]);
        if (lane == 0) {
            atomicAdd(&lc[a], 1.0f);
            atomicAdd(&lf[a], x[n * 7 + 6]);
        }
    }
    __syncthreads();
    atomicAdd(&zsum[t], lz[t]);
    if (t < KCL) {
        atomicAdd(&cntK[t], lc[t]);
        atomicAdd(&cfK[t], lf[t]);
    }
}

// ---------------------------------------------------------------- k_head: actor head + outputs
__global__ __launch_bounds__(256) void k_head(const float* __restrict__ zsum, const float* __restrict__ cntK,
                                              const float* __restrict__ cfK, const float* __restrict__ b2,
                                              const float* __restrict__ A1, const float* __restrict__ c1,
                                              const float* __restrict__ A2, const float* __restrict__ c2,
                                              float* __restrict__ out) {
    __shared__ float zcf[KCL][65];
    __shared__ float logits[KCL];
    int t = threadIdx.x;                       // 256
    int k = t >> 6, c = t & 63;
    float cn = cntK[k];
    float z = (cn > 0.f) ? (zsum[k * 64 + c] / fmaxf(cn, 1.0f) + b2[c]) : 0.0f;
    zcf[k][c] = z;
    out[4 + k * 64 + c] = z;                   // z_flat
    if (c == 0) zcf[k][64] = (cn > 0.f) ? (cfK[k] / fmaxf(cn, 1.0f)) : 0.0f;
    __syncthreads();
    if (t < 64) {
        int j = t;
#pragma unroll
        for (int kk = 0; kk < KCL; kk++) {
            float acc = 0.0f;
            for (int i = 0; i < 65; i++) acc += zcf[kk][i] * A1[i * 64 + j];
            float hr = fmaxf(acc + c1[j], 0.0f);
            float contrib = hr * A2[j];
            for (int off = 32; off; off >>= 1) contrib += __shfl_down(contrib, off, 64);
            if (j == 0) logits[kk] = contrib + c2[0];
        }
    }
    __syncthreads();
    if (t == 0) {
        float m = fmaxf(fmaxf(logits[0], logits[1]), fmaxf(logits[2], logits[3]));
        float e0 = expf(logits[0] - m), e1 = expf(logits[1] - m);
        float e2 = expf(logits[2] - m), e3 = expf(logits[3] - m);
        float s = e0 + e1 + e2 + e3;
        out[0] = e0 / s; out[1] = e1 / s; out[2] = e2 / s; out[3] = e3 / s;
    }
}

extern "C" void kernel_launch(void* const* d_in, const int* in_sizes, int n_in,
                              void* d_out, int out_size, void* d_ws, size_t ws_size,
                              hipStream_t stream) {
    const float* x      = (const float*)d_in[0];
    const int*   ei     = (const int*)d_in[1];
    const float* eattr  = (const float*)d_in[2];
    const int*   assign = (const int*)d_in[3];
    const float* W1     = (const float*)d_in[4];
    const float* as1    = (const float*)d_in[5];
    const float* ad1    = (const float*)d_in[6];
    const float* We1    = (const float*)d_in[7];
    const float* ae1    = (const float*)d_in[8];
    const float* b1     = (const float*)d_in[9];
    const float* W2     = (const float*)d_in[10];
    const float* as2    = (const float*)d_in[11];
    const float* ad2    = (const float*)d_in[12];
    const float* We2    = (const float*)d_in[13];
    const float* ae2    = (const float*)d_in[14];
    const float* b2     = (const float*)d_in[15];
    const float* A1     = (const float*)d_in[16];
    const float* c1     = (const float*)d_in[17];
    const float* A2     = (const float*)d_in[18];
    const float* c2     = (const float*)d_in[19];
    float* out = (float*)d_out;

    const int N_ = in_sizes[0] / 7;            // 50000
    const int E_ = in_sizes[2];                // 800000
    const int NB = (N_ + 255) / 256;
    const int BW = (N_ + NBUCK - 1) / NBUCK;   // 196 rows per bucket
    const int* srcA = ei;
    const int* dstA = ei + E_;

    // ---- workspace layout ----
    float* ws = (float*)d_ws;
    size_t Nz = (size_t)N_;
    float* al_s1   = ws;                       // 4N
    float* al_d1   = al_s1 + 4 * Nz;           // 4N
    float* al_s2   = al_d1 + 4 * Nz;           // N
    float* al_d2   = al_s2 + Nz;               // N
    float* ce1     = al_d2 + Nz;               // 4
    float* ce2     = ce1 + 4;                  // 4 (padded)
    float* zsum    = ce2 + 4;                  // 256
    float* cntK    = zsum + 256;               // 4
    float* cfK     = cntK + 4;                 // 4
    float* u_s     = cfK + 4;                  // 256
    float* u_d     = u_s + 256;                // 256
    float* xpad    = ws + 10 * Nz + 1024;      // 8N
    float* xacc    = xpad + 8 * Nz;            // 32N
    unsigned short* xw2b = (unsigned short*)(xacc + 32 * Nz);  // 64N bf16 (= 32N floats)
    float* h2      = (float*)(xw2b + 64 * Nz); // 64N
    uintptr_t pp   = (uintptr_t)(h2 + 64 * Nz);
    u64* gbuck     = (u64*)((pp + 7) & ~(uintptr_t)7);       // NBUCK*BCAP u64 (8 MB)
    u64* gpacked   = gbuck + (size_t)NBUCK * BCAP;           // NBUCK*BCAP u64 (8 MB)
    unsigned int* gtail = (unsigned int*)(gpacked + (size_t)NBUCK * BCAP);  // 256
    int2* idx2     = (int2*)(gtail + 256);                   // N int2
    unsigned short* W2T = (unsigned short*)(idx2 + Nz);      // 64*256 bf16

    // ---- zero the tiny accumulators ----
    hipMemsetAsync(zsum, 0, 264 * sizeof(float), stream);
    hipMemsetAsync(gtail, 0, NBUCK * sizeof(unsigned int), stream);

    // ---- constants + transpose + node prep (one dispatch) ----
    k_prep_all<<<NB, 256, 0, stream>>>(x, W1, W2, as1, ad1, as2, ad2,
                                       We1, ae1, We2, ae2,
                                       ce1, ce2, u_s, u_d, W2T,
                                       xpad, al_s1, al_d1, N_);

    // ---- two-pass binned CSR build (line-dense writes) ----
    k_bin<<<(E_ + 256 * EPT - 1) / (256 * EPT), 256, 0, stream>>>(srcA, dstA, eattr, gtail, gbuck, E_, BW);
    k_scatter2<<<NBUCK, 256, 0, stream>>>(gtail, gbuck, gpacked, idx2, N_, BW);

    // ---- conv1 ----
    k_agg1f<<<(4 * N_ + 255) / 256, 256, 0, stream>>>(idx2, gpacked, al_s1, al_d1, ce1, xpad, xacc, N_);

    // ---- conv2: MFMA h1-gen + GEMM (bf16 out), softmax-aggregate (1 wave/dst), pooling ----
    k_xw2g<<<(N_ + 15) / 16, 256, 0, stream>>>(xacc, W1, b1, W2T, u_s, u_d,
                                               xw2b, al_s2, al_d2, N_);
    k_agg2f<<<(N_ + 3) / 4, 256, 0, stream>>>(idx2, gpacked, al_s2, al_d2, ce2, xw2b, h2, N_);
    k_pool<<<256, 256, 0, stream>>>(h2, x, assign, zsum, cntK, cfK, N_);

    // ---- head ----
    k_head<<<1, 256, 0, stream>>>(zsum, cntK, cfK, b2, A1, c1, A2, c2, out);
}